// Round 3
// baseline (403.436 us; speedup 1.0000x reference)
//
#include <hip/hip_runtime.h>

#define NB 8
#define NC 128
#define NM 4096
#define FRAG 512   // shorts per (tile,ks) fragment block: 64 lanes x 8

typedef __attribute__((ext_vector_type(8))) short short8;
typedef __attribute__((ext_vector_type(4))) float floatx4;

#define MFMA(a, b, c) __builtin_amdgcn_mfma_f32_16x16x32_bf16(a, b, c, 0, 0, 0)
#define EXP2F(x) __builtin_amdgcn_exp2f(x)

union S8U { short8 v; uint2 u2[2]; };

__device__ __forceinline__ unsigned pack2bf(float a, float b) {
    unsigned ua = __float_as_uint(a);
    unsigned ub = __float_as_uint(b);
    ua += 0x7fffu + ((ua >> 16) & 1u);
    ub += 0x7fffu + ((ub >> 16) & 1u);
    return (ua >> 16) | (ub & 0xffff0000u);
}

// Single-instruction packed f32->bf16 (RNE), same rounding as pack2bf.
__device__ __forceinline__ unsigned cvt_pk_bf16(float a, float b) {
    unsigned r;
    asm("v_cvt_pk_bf16_f32 %0, %1, %2" : "=v"(r) : "v"(a), "v"(b));
    return r;
}

// QK softmax scale folded into fX: sqrt(2^-3.5 * log2(e)); RS = 1/SF.
__constant__ float SF_C = 0.35712442f;
__constant__ float RS_C = 2.8001530f;

// ---------------------------------------------------------------------------
// Fragment-order layouts (one contiguous 1024B chunk per wave fragment load):
//   fX[b][mt(256)][ks(4)][lane(64)][8] : lane l=(lq*16+lm) holds
//       f-row (mt*16+lm), cols ks*32+lq*8..+7, scaled by SF, bf16.
//   gX[b][nblk(32)][ot(8)][k2(4)][lane(64)][8] : lane l holds
//       g-row o=ot*16+lm, cols n=nblk*128+k2*32+lq*8..+7, bf16.
// ---------------------------------------------------------------------------

// P1: fX from f (transpose + scale + bf16 + fragment order)
__global__ __launch_bounds__(256) void k_prep_f(
    const float* __restrict__ f, unsigned short* __restrict__ fX)
{
    __shared__ float Ls[128][65];
    const int tid = threadIdx.x;
    const int b   = blockIdx.x & 7;
    const int m0  = (blockIdx.x >> 3) * 64;
    const float* fb = f + (size_t)b * NC * NM;
    #pragma unroll
    for (int k = 0; k < 32; ++k) {
        int idx = tid + k * 256;
        int c = idx >> 6, mm = idx & 63;
        Ls[c][mm] = fb[(size_t)c * NM + m0 + mm];
    }
    __syncthreads();
    const float sf = SF_C;
    const int m  = tid >> 2;
    const int ks = tid & 3;
    const int ch = ks * 32;
    unsigned pk[16];
    #pragma unroll
    for (int i = 0; i < 16; ++i)
        pk[i] = pack2bf(Ls[ch + 2 * i][m] * sf, Ls[ch + 2 * i + 1][m] * sf);
    const int Mg  = m0 + m;
    const int mt  = Mg >> 4;
    const int lmm = Mg & 15;
    unsigned short* dst = fX + ((size_t)b * 256 + mt) * 4 * FRAG + ks * FRAG;
    #pragma unroll
    for (int q = 0; q < 4; ++q)
        *(uint4*)(dst + (q * 16 + lmm) * 8) =
            make_uint4(pk[4 * q], pk[4 * q + 1], pk[4 * q + 2], pk[4 * q + 3]);
}

// ---------------------------------------------------------------------------
// P2 (MFMA): gX = bf16( (w1a*RS) . fX ) in fragment order.
// grid 256 = b(8) x nblk(32); 4 waves; wave wv owns ot = 2wv, 2wv+1.
// ---------------------------------------------------------------------------
__global__ __launch_bounds__(256) void k_prep_g(
    const unsigned short* __restrict__ fX, const float* __restrict__ w1,
    unsigned short* __restrict__ gX)
{
    __shared__ unsigned short gt[128][136];   // [o][n-local]
    const int tid = threadIdx.x;
    const int wv  = tid >> 6;
    const int l   = tid & 63;
    const int lm  = l & 15;
    const int lq  = l >> 4;
    const int b    = blockIdx.x & 7;
    const int nblk = blockIdx.x >> 3;

    const float rs = RS_C;

    short8 wf2[2][4];
    #pragma unroll
    for (int j = 0; j < 2; ++j) {
        const int o = (wv * 2 + j) * 16 + lm;
        #pragma unroll
        for (int ks = 0; ks < 4; ++ks) {
            const float* wp = w1 + (size_t)o * (2 * NC) + ks * 32 + lq * 8;
            S8U t;
            t.u2[0] = make_uint2(pack2bf(wp[0] * rs, wp[1] * rs),
                                 pack2bf(wp[2] * rs, wp[3] * rs));
            t.u2[1] = make_uint2(pack2bf(wp[4] * rs, wp[5] * rs),
                                 pack2bf(wp[6] * rs, wp[7] * rs));
            wf2[j][ks] = t.v;
        }
    }

    const unsigned short* fXb = fX + (size_t)b * NM * NC;
    #pragma unroll 2
    for (int nt = 0; nt < 8; ++nt) {
        short8 af[4];
        #pragma unroll
        for (int ks = 0; ks < 4; ++ks)
            af[ks] = *(const short8*)
                (fXb + (size_t)(nblk * 8 + nt) * 4 * FRAG + ks * FRAG + l * 8);
        #pragma unroll
        for (int j = 0; j < 2; ++j) {
            floatx4 D = {0.f, 0.f, 0.f, 0.f};
            #pragma unroll
            for (int ks = 0; ks < 4; ++ks)
                D = MFMA(af[ks], wf2[j][ks], D);
            *(uint2*)&gt[(wv * 2 + j) * 16 + lm][nt * 16 + lq * 4] =
                make_uint2(pack2bf(D[0], D[1]), pack2bf(D[2], D[3]));
        }
    }
    __syncthreads();

    #pragma unroll
    for (int j = 0; j < 2; ++j) {
        const int ot = wv * 2 + j;
        #pragma unroll
        for (int k2 = 0; k2 < 4; ++k2) {
            uint4 v = *(const uint4*)&gt[ot * 16 + lm][k2 * 32 + lq * 8];
            *(uint4*)(gX + (((size_t)b * 32 + nblk) * 8 + ot) * 4 * FRAG
                      + k2 * FRAG + l * 8) = v;
        }
    }
}

// ---------------------------------------------------------------------------
// Main: MFMA flash attention + fused cls head.
// 512 threads = 2 wave-groups of 4; group g handles n-half g (16 iters of
// TN=128). Each group is the proven round-1 4-wave kernel with its own
// double-buffered Ps (4 x 16KB = 64KB LDS). At the end, group 1 dumps its
// unnormalized u into the dead Ps area; group 0 merges and runs the fused
// head. grid 512 = b(8) x mblock(64); 2 blocks/CU -> 16 waves/CU (4/SIMD).
// ---------------------------------------------------------------------------
__global__ __launch_bounds__(512, 4) void k_attn(
    const unsigned short* __restrict__ fX,
    const unsigned short* __restrict__ gX,
    const float* __restrict__ w1,
    const float* __restrict__ b1v, const float* __restrict__ gammav,
    const float* __restrict__ betav, const float* __restrict__ rmeanv,
    const float* __restrict__ rvarv, const float* __restrict__ w2v,
    const float* __restrict__ b2v, float* __restrict__ out)
{
    __shared__ __align__(16) char smem[65536];   // [g][buf][16KB] Ps; reused in epilogue

    const int tid = threadIdx.x;
    const int w   = tid >> 6;        // 0..7
    const int g   = w >> 2;          // n-half group
    const int wg  = w & 3;           // wave index within group
    const int l   = tid & 63;
    const int lm  = l & 15;
    const int lq  = l >> 4;
    const int b   = blockIdx.x & 7;
    const int m0  = (blockIdx.x >> 3) * 64;

    char* ps_g = smem + g * 32768;

    // --- Ps addressing (fragment order + XOR swizzle), per-lane constant ---
    const int lq0 = lq & 1;
    const int lq1 = lq >> 1;
    const int lm3 = lm >> 3;
    const unsigned Xsw = (unsigned)(((lq1 << 1) | lm3) << 4);
    const unsigned wofsA =
        ((((unsigned)(wg >> 1) * 4 * 16) + ((unsigned)(2 * (wg & 1) + lq1) * 16)
          + (unsigned)lm) * 16 + (unsigned)(8 * lq0)) ^ Xsw;
    const unsigned rofs = ((unsigned)l * 16) ^ ((((unsigned)l >> 3) & 3u) << 4);

    const unsigned short* fXb = fX + (size_t)b * NM * NC;
    const unsigned short* gXb = gX + (size_t)b * NC * NM;

    short8 qf[4][4];
    {
        const int qt0 = m0 >> 4;
        #pragma unroll
        for (int mt = 0; mt < 4; ++mt)
            #pragma unroll
            for (int ks = 0; ks < 4; ++ks)
                qf[mt][ks] = *(const short8*)
                    (fXb + (size_t)(qt0 + mt) * 4 * FRAG + ks * FRAG + l * 8);
    }

    // group g starts at global n-tile g*128
    const unsigned short* kpA = fXb + (size_t)(g * 128 + wg) * 4 * FRAG + l * 8;
    const unsigned short* kpB = fXb + (size_t)(g * 128 + 4 + wg) * 4 * FRAG + l * 8;
    const unsigned short* gp0 = gXb + (size_t)(g * 128 + 2 * wg) * 4 * FRAG + l * 8;
    const unsigned short* gp1 = gXb + (size_t)(g * 128 + 2 * wg + 1) * 4 * FRAG + l * 8;

    short8 kfA[4], kfB[4], gf0[4], gf1[4];
    #pragma unroll
    for (int ks = 0; ks < 4; ++ks) {
        kfA[ks] = *(const short8*)(kpA + ks * FRAG);
        kfB[ks] = *(const short8*)(kpB + ks * FRAG);
    }
    #pragma unroll
    for (int k2 = 0; k2 < 4; ++k2) {
        gf0[k2] = *(const short8*)(gp0 + k2 * FRAG);
        gf1[k2] = *(const short8*)(gp1 + k2 * FRAG);
    }

    floatx4 u[4][2];
    float lsum[4] = {0.f, 0.f, 0.f, 0.f};
    #pragma unroll
    for (int mt = 0; mt < 4; ++mt) {
        u[mt][0] = (floatx4){0.f, 0.f, 0.f, 0.f};
        u[mt][1] = (floatx4){0.f, 0.f, 0.f, 0.f};
    }

    for (int it = 0; it < 16; ++it) {
        char* psb = ps_g + (it & 1) * 16384;

        floatx4 svA[4], svB[4];
        __builtin_amdgcn_s_setprio(1);
        #pragma unroll
        for (int mt = 0; mt < 4; ++mt) {
            floatx4 a = {-24.f, -24.f, -24.f, -24.f};
            floatx4 bb = {-24.f, -24.f, -24.f, -24.f};
            #pragma unroll
            for (int ks = 0; ks < 4; ++ks) {
                a  = MFMA(kfA[ks], qf[mt][ks], a);
                bb = MFMA(kfB[ks], qf[mt][ks], bb);
            }
            svA[mt] = a; svB[mt] = bb;
        }
        __builtin_amdgcn_s_setprio(0);
        {
            const int kstep = (it < 15) ? 8 * 4 * FRAG : 0;
            kpA += kstep; kpB += kstep;
            #pragma unroll
            for (int ks = 0; ks < 4; ++ks) {
                kfA[ks] = *(const short8*)(kpA + ks * FRAG);
                kfB[ks] = *(const short8*)(kpB + ks * FRAG);
            }
        }

        #pragma unroll
        for (int mt = 0; mt < 4; ++mt) {
            float pA0 = EXP2F(svA[mt][0]);
            float pA1 = EXP2F(svA[mt][1]);
            float pA2 = EXP2F(svA[mt][2]);
            float pA3 = EXP2F(svA[mt][3]);
            float pB0 = EXP2F(svB[mt][0]);
            float pB1 = EXP2F(svB[mt][1]);
            float pB2 = EXP2F(svB[mt][2]);
            float pB3 = EXP2F(svB[mt][3]);
            lsum[mt] += ((pA0 + pA1) + (pA2 + pA3)) +
                        ((pB0 + pB1) + (pB2 + pB3));
            *(uint2*)(psb + mt * 4096 + wofsA) =
                make_uint2(cvt_pk_bf16(pA0, pA1), cvt_pk_bf16(pA2, pA3));
            *(uint2*)(psb + mt * 4096 + wofsA + 2048) =
                make_uint2(cvt_pk_bf16(pB0, pB1), cvt_pk_bf16(pB2, pB3));
        }
        __syncthreads();

        #pragma unroll
        for (int k2 = 0; k2 < 4; ++k2) {
            short8 pf[4];
            #pragma unroll
            for (int mt = 0; mt < 4; ++mt)
                pf[mt] = *(const short8*)(psb + mt * 4096 + k2 * 1024 + rofs);
            __builtin_amdgcn_s_setprio(1);
            #pragma unroll
            for (int mt = 0; mt < 4; ++mt) {
                u[mt][0] = MFMA(pf[mt], gf0[k2], u[mt][0]);
                u[mt][1] = MFMA(pf[mt], gf1[k2], u[mt][1]);
            }
            __builtin_amdgcn_s_setprio(0);
        }
        {
            const int gstep = (it < 15) ? 8 * 4 * FRAG : 0;
            gp0 += gstep; gp1 += gstep;
            #pragma unroll
            for (int k2 = 0; k2 < 4; ++k2) {
                gf0[k2] = *(const short8*)(gp0 + k2 * FRAG);
                gf1[k2] = *(const short8*)(gp1 + k2 * FRAG);
            }
        }
    }

    // ---- epilogue: merge groups, fused head ----
    float* lpartf = (float*)smem;             // [8][64]  (2KB, dead Ps area)
    float* opartf = (float*)(smem + 2048);    // [4][64]  (1KB)
    float* udump  = (float*)(smem + 32768);   // 32KB (group-1 Ps area)

    #pragma unroll
    for (int mt = 0; mt < 4; ++mt) {
        lsum[mt] += __shfl_xor(lsum[mt], 16);
        lsum[mt] += __shfl_xor(lsum[mt], 32);
    }
    if (lq == 0) {
        #pragma unroll
        for (int mt = 0; mt < 4; ++mt)
            lpartf[w * 64 + mt * 16 + lm] = lsum[mt];
    }
    __syncthreads();   // B1: all PV reads done; lpart visible

    if (w >= 4) {      // group 1 dumps unnormalized u
        float* ud = udump + (size_t)wg * 2048 + l * 4;
        #pragma unroll
        for (int mt = 0; mt < 4; ++mt)
            #pragma unroll
            for (int j = 0; j < 2; ++j)
                *(floatx4*)(ud + (mt * 2 + j) * 256) = u[mt][j];
    }
    __syncthreads();   // B2

    if (w < 4) {
        {
            const float* ud = udump + (size_t)w * 2048 + l * 4;
            #pragma unroll
            for (int mt = 0; mt < 4; ++mt)
                #pragma unroll
                for (int j = 0; j < 2; ++j)
                    u[mt][j] += *(const floatx4*)(ud + (mt * 2 + j) * 256);
        }

        floatx4 hacc[4][2];
        {
            const float rs = RS_C;
            #pragma unroll
            for (int j = 0; j < 2; ++j) {
                int o = w * 32 + j * 16 + lm;
                short8 wf[4];
                #pragma unroll
                for (int ks = 0; ks < 4; ++ks) {
                    const float* wp = w1 + (size_t)o * (2 * NC) + NC + ks * 32 + lq * 8;
                    S8U t;
                    t.u2[0] = make_uint2(pack2bf(wp[0] * rs, wp[1] * rs),
                                         pack2bf(wp[2] * rs, wp[3] * rs));
                    t.u2[1] = make_uint2(pack2bf(wp[4] * rs, wp[5] * rs),
                                         pack2bf(wp[6] * rs, wp[7] * rs));
                    wf[ks] = t.v;
                }
                #pragma unroll
                for (int mt = 0; mt < 4; ++mt) {
                    floatx4 a = {0.f, 0.f, 0.f, 0.f};
                    #pragma unroll
                    for (int ks = 0; ks < 4; ++ks)
                        a = MFMA(qf[mt][ks], wf[ks], a);
                    hacc[mt][j] = a;
                }
            }
        }

        float Abn[2], Dbn[2], W2[2];
        #pragma unroll
        for (int j = 0; j < 2; ++j) {
            int o = w * 32 + j * 16 + lm;
            float Ar = gammav[o] * rsqrtf(rvarv[o] + 1e-5f);
            Abn[j] = Ar;
            Dbn[j] = (b1v[o] - rmeanv[o]) * Ar + betav[o];
            W2[j]  = w2v[o];
        }
        float av[16];
        #pragma unroll
        for (int mt = 0; mt < 4; ++mt) {
            float4 Lt = make_float4(0.f, 0.f, 0.f, 0.f);
            #pragma unroll
            for (int p = 0; p < 8; ++p) {
                float4 Lp = *(const float4*)&lpartf[p * 64 + mt * 16 + lq * 4];
                Lt.x += Lp.x; Lt.y += Lp.y; Lt.z += Lp.z; Lt.w += Lp.w;
            }
            #pragma unroll
            for (int r = 0; r < 4; ++r) {
                float rl = 1.f / ((const float*)&Lt)[r];
                float t0 = Abn[0] * (u[mt][0][r] * rl + hacc[mt][0][r]) + Dbn[0];
                float t1 = Abn[1] * (u[mt][1][r] * rl + hacc[mt][1][r]) + Dbn[1];
                t0 = t0 >= 0.f ? t0 : 0.01f * t0;
                t1 = t1 >= 0.f ? t1 : 0.01f * t1;
                av[mt * 4 + r] = W2[0] * t0 + W2[1] * t1;
            }
        }
        #pragma unroll
        for (int i = 0; i < 16; ++i) {
            av[i] += __shfl_xor(av[i], 1);
            av[i] += __shfl_xor(av[i], 2);
            av[i] += __shfl_xor(av[i], 4);
            av[i] += __shfl_xor(av[i], 8);
        }
        if (lm == 0) {
            #pragma unroll
            for (int mt = 0; mt < 4; ++mt)
                #pragma unroll
                for (int r = 0; r < 4; ++r)
                    opartf[w * 64 + mt * 16 + lq * 4 + r] = av[mt * 4 + r];
        }
    }
    __syncthreads();   // B3
    if (tid < 64)
        out[(size_t)b * NM + m0 + tid] =
            b2v[0] + opartf[tid] + opartf[64 + tid] +
            opartf[128 + tid] + opartf[192 + tid];
}

extern "C" void kernel_launch(void* const* d_in, const int* in_sizes, int n_in,
                              void* d_out, int out_size, void* d_ws, size_t ws_size,
                              hipStream_t stream) {
    const float* f     = (const float*)d_in[0];
    const float* w1    = (const float*)d_in[1];
    const float* b1    = (const float*)d_in[2];
    const float* gamma = (const float*)d_in[3];
    const float* beta  = (const float*)d_in[4];
    const float* rmean = (const float*)d_in[5];
    const float* rvar  = (const float*)d_in[6];
    const float* w2    = (const float*)d_in[7];
    const float* b2    = (const float*)d_in[8];
    float* out = (float*)d_out;

    unsigned short* fX = (unsigned short*)d_ws;              // 8 MB bf16 frag-order
    unsigned short* gX = fX + (size_t)NB * NM * NC;          // 8 MB bf16 frag-order

    hipLaunchKernelGGL(k_prep_f, dim3(512), dim3(256), 0, stream, f, fX);
    hipLaunchKernelGGL(k_prep_g, dim3(256), dim3(256), 0, stream, fX, w1, gX);
    hipLaunchKernelGGL(k_attn,   dim3(512), dim3(512), 0, stream,
                       fX, gX, w1, b1, gamma, beta, rmean, rvar, w2, b2, out);
}

// Round 5
// 177.041 us; speedup vs baseline: 2.2788x; 2.2788x over previous
//
#include <hip/hip_runtime.h>

#define NB 8
#define NC 128
#define NM 4096
#define FRAG 512   // shorts per (tile,ks) fragment block: 64 lanes x 8

typedef __attribute__((ext_vector_type(8))) short short8;
typedef __attribute__((ext_vector_type(4))) float floatx4;

#define MFMA(a, b, c) __builtin_amdgcn_mfma_f32_16x16x32_bf16(a, b, c, 0, 0, 0)
#define EXP2F(x) __builtin_amdgcn_exp2f(x)

union S8U { short8 v; uint2 u2[2]; };

__device__ __forceinline__ unsigned pack2bf(float a, float b) {
    unsigned ua = __float_as_uint(a);
    unsigned ub = __float_as_uint(b);
    ua += 0x7fffu + ((ua >> 16) & 1u);
    ub += 0x7fffu + ((ub >> 16) & 1u);
    return (ua >> 16) | (ub & 0xffff0000u);
}

// Single-instruction packed f32->bf16 (RNE), same rounding as pack2bf.
__device__ __forceinline__ unsigned cvt_pk_bf16(float a, float b) {
    unsigned r;
    asm("v_cvt_pk_bf16_f32 %0, %1, %2" : "=v"(r) : "v"(a), "v"(b));
    return r;
}

// QK softmax scale folded into fX: sqrt(2^-3.5 * log2(e)); RS = 1/SF.
__constant__ float SF_C = 0.35712442f;
__constant__ float RS_C = 2.8001530f;

// ---------------------------------------------------------------------------
// Fragment-order layouts (one contiguous 1024B chunk per wave fragment load):
//   fX[b][mt(256)][ks(4)][lane(64)][8] : lane l=(lq*16+lm) holds
//       f-row (mt*16+lm), cols ks*32+lq*8..+7, scaled by SF, bf16.
//   gX[b][nblk(32)][ot(8)][k2(4)][lane(64)][8] : lane l holds
//       g-row o=ot*16+lm, cols n=nblk*128+k2*32+lq*8..+7, bf16.
// ---------------------------------------------------------------------------

// P1: fX from f (transpose + scale + bf16 + fragment order)
__global__ __launch_bounds__(256) void k_prep_f(
    const float* __restrict__ f, unsigned short* __restrict__ fX)
{
    __shared__ float Ls[128][65];
    const int tid = threadIdx.x;
    const int b   = blockIdx.x & 7;
    const int m0  = (blockIdx.x >> 3) * 64;
    const float* fb = f + (size_t)b * NC * NM;
    #pragma unroll
    for (int k = 0; k < 32; ++k) {
        int idx = tid + k * 256;
        int c = idx >> 6, mm = idx & 63;
        Ls[c][mm] = fb[(size_t)c * NM + m0 + mm];
    }
    __syncthreads();
    const float sf = SF_C;
    const int m  = tid >> 2;
    const int ks = tid & 3;
    const int ch = ks * 32;
    unsigned pk[16];
    #pragma unroll
    for (int i = 0; i < 16; ++i)
        pk[i] = pack2bf(Ls[ch + 2 * i][m] * sf, Ls[ch + 2 * i + 1][m] * sf);
    const int Mg  = m0 + m;
    const int mt  = Mg >> 4;
    const int lmm = Mg & 15;
    unsigned short* dst = fX + ((size_t)b * 256 + mt) * 4 * FRAG + ks * FRAG;
    #pragma unroll
    for (int q = 0; q < 4; ++q)
        *(uint4*)(dst + (q * 16 + lmm) * 8) =
            make_uint4(pk[4 * q], pk[4 * q + 1], pk[4 * q + 2], pk[4 * q + 3]);
}

// ---------------------------------------------------------------------------
// P2 (MFMA): gX = bf16( (w1a*RS) . fX ) in fragment order.
// grid 256 = b(8) x nblk(32); 4 waves; wave wv owns ot = 2wv, 2wv+1.
// ---------------------------------------------------------------------------
__global__ __launch_bounds__(256) void k_prep_g(
    const unsigned short* __restrict__ fX, const float* __restrict__ w1,
    unsigned short* __restrict__ gX)
{
    __shared__ unsigned short gt[128][136];   // [o][n-local]
    const int tid = threadIdx.x;
    const int wv  = tid >> 6;
    const int l   = tid & 63;
    const int lm  = l & 15;
    const int lq  = l >> 4;
    const int b    = blockIdx.x & 7;
    const int nblk = blockIdx.x >> 3;

    const float rs = RS_C;

    short8 wf2[2][4];
    #pragma unroll
    for (int j = 0; j < 2; ++j) {
        const int o = (wv * 2 + j) * 16 + lm;
        #pragma unroll
        for (int ks = 0; ks < 4; ++ks) {
            const float* wp = w1 + (size_t)o * (2 * NC) + ks * 32 + lq * 8;
            S8U t;
            t.u2[0] = make_uint2(pack2bf(wp[0] * rs, wp[1] * rs),
                                 pack2bf(wp[2] * rs, wp[3] * rs));
            t.u2[1] = make_uint2(pack2bf(wp[4] * rs, wp[5] * rs),
                                 pack2bf(wp[6] * rs, wp[7] * rs));
            wf2[j][ks] = t.v;
        }
    }

    const unsigned short* fXb = fX + (size_t)b * NM * NC;
    #pragma unroll 2
    for (int nt = 0; nt < 8; ++nt) {
        short8 af[4];
        #pragma unroll
        for (int ks = 0; ks < 4; ++ks)
            af[ks] = *(const short8*)
                (fXb + (size_t)(nblk * 8 + nt) * 4 * FRAG + ks * FRAG + l * 8);
        #pragma unroll
        for (int j = 0; j < 2; ++j) {
            floatx4 D = {0.f, 0.f, 0.f, 0.f};
            #pragma unroll
            for (int ks = 0; ks < 4; ++ks)
                D = MFMA(af[ks], wf2[j][ks], D);
            *(uint2*)&gt[(wv * 2 + j) * 16 + lm][nt * 16 + lq * 4] =
                make_uint2(pack2bf(D[0], D[1]), pack2bf(D[2], D[3]));
        }
    }
    __syncthreads();

    #pragma unroll
    for (int j = 0; j < 2; ++j) {
        const int ot = wv * 2 + j;
        #pragma unroll
        for (int k2 = 0; k2 < 4; ++k2) {
            uint4 v = *(const uint4*)&gt[ot * 16 + lm][k2 * 32 + lq * 8];
            *(uint4*)(gX + (((size_t)b * 32 + nblk) * 8 + ot) * 4 * FRAG
                      + k2 * FRAG + l * 8) = v;
        }
    }
}

// ---------------------------------------------------------------------------
// Main: MFMA flash attention + fused cls head. Occupancy-first geometry:
// 32 m-rows per block, 4 waves, TN=64/iter (wave w owns ktile 4*it+w),
// 64 iters. Per-wave regs ~110 (qf32+kf16+gf16+sv8+u16+misc) -> fits the
// 128-reg cap for 4 waves/SIMD. grid 1024 = b(8) x mblk(128) -> 4 blk/CU.
// Ps per buf: [mt(2)][k2(2)][slot(64)][16B] = 4KB, double-buffered (8KB).
// Same fragment-order + XOR swizzle + cvt_pk + setprio as round-1.
// ---------------------------------------------------------------------------
__global__ __launch_bounds__(256, 4) void k_attn(
    const unsigned short* __restrict__ fX,
    const unsigned short* __restrict__ gX,
    const float* __restrict__ w1,
    const float* __restrict__ b1v, const float* __restrict__ gammav,
    const float* __restrict__ betav, const float* __restrict__ rmeanv,
    const float* __restrict__ rvarv, const float* __restrict__ w2v,
    const float* __restrict__ b2v, float* __restrict__ out)
{
    __shared__ __align__(16) char smem[8192];   // Ps double buffer; epilogue reuse

    const int tid = threadIdx.x;
    const int w   = tid >> 6;
    const int l   = tid & 63;
    const int lm  = l & 15;
    const int lq  = l >> 4;
    const int b   = blockIdx.x & 7;
    const int m0  = (blockIdx.x >> 3) * 32;

    // Ps addressing (fragment order + XOR swizzle), per-lane constant.
    // QK out: lane holds S[n = w*16 + lq*4 + r][m = lm]. k2 = w>>1;
    // slotq = 2*(w&1) + (lq>>1); elem base = 4*(lq&1).
    const int lq0 = lq & 1;
    const int lq1 = lq >> 1;
    const int lm3 = lm >> 3;
    const unsigned Xsw = (unsigned)(((lq1 << 1) | lm3) << 4);
    const unsigned wofs =
        ((unsigned)(w >> 1) * 1024 +
         ((((unsigned)(2 * (w & 1) + lq1) * 16) + (unsigned)lm) * 16 +
          (unsigned)(8 * lq0))) ^ Xsw;
    const unsigned rofs = ((unsigned)l * 16) ^ ((((unsigned)l >> 3) & 3u) << 4);

    const unsigned short* fXb = fX + (size_t)b * NM * NC;
    const unsigned short* gXb = gX + (size_t)b * NC * NM;

    short8 qf[2][4];
    {
        const int qt0 = m0 >> 4;
        #pragma unroll
        for (int mt = 0; mt < 2; ++mt)
            #pragma unroll
            for (int ks = 0; ks < 4; ++ks)
                qf[mt][ks] = *(const short8*)
                    (fXb + (size_t)(qt0 + mt) * 4 * FRAG + ks * FRAG + l * 8);
    }

    // K stream: wave w handles global ktile 4*it + w.
    const unsigned short* kp = fXb + (size_t)w * 4 * FRAG + l * 8;
    short8 kf[4];
    #pragma unroll
    for (int ks = 0; ks < 4; ++ks)
        kf[ks] = *(const short8*)(kp + ks * FRAG);

    // G stream: wave w owns o-tiles 2w, 2w+1; iter it covers nblk=it>>1,
    // k2 pair (it&1)*2 + {0,1}.
    short8 gf[2][2];
    #pragma unroll
    for (int j = 0; j < 2; ++j)
        #pragma unroll
        for (int k2l = 0; k2l < 2; ++k2l)
            gf[j][k2l] = *(const short8*)
                (gXb + ((size_t)(2 * w + j) * 4 + k2l) * FRAG + l * 8);

    floatx4 u[2][2];
    float lsum[2] = {0.f, 0.f};
    #pragma unroll
    for (int mt = 0; mt < 2; ++mt) {
        u[mt][0] = (floatx4){0.f, 0.f, 0.f, 0.f};
        u[mt][1] = (floatx4){0.f, 0.f, 0.f, 0.f};
    }

    for (int it = 0; it < 64; ++it) {
        char* psb = smem + (it & 1) * 4096;

        floatx4 sv[2];
        __builtin_amdgcn_s_setprio(1);
        #pragma unroll
        for (int mt = 0; mt < 2; ++mt) {
            floatx4 a = {-24.f, -24.f, -24.f, -24.f};
            #pragma unroll
            for (int ks = 0; ks < 4; ++ks)
                a = MFMA(kf[ks], qf[mt][ks], a);
            sv[mt] = a;
        }
        __builtin_amdgcn_s_setprio(0);
        {
            const int kstep = (it < 63) ? 16 * FRAG : 0;
            kp += kstep;
            #pragma unroll
            for (int ks = 0; ks < 4; ++ks)
                kf[ks] = *(const short8*)(kp + ks * FRAG);
        }

        #pragma unroll
        for (int mt = 0; mt < 2; ++mt) {
            float p0 = EXP2F(sv[mt][0]);
            float p1 = EXP2F(sv[mt][1]);
            float p2 = EXP2F(sv[mt][2]);
            float p3 = EXP2F(sv[mt][3]);
            lsum[mt] += (p0 + p1) + (p2 + p3);
            *(uint2*)(psb + mt * 2048 + wofs) =
                make_uint2(cvt_pk_bf16(p0, p1), cvt_pk_bf16(p2, p3));
        }
        __syncthreads();

        #pragma unroll
        for (int k2l = 0; k2l < 2; ++k2l) {
            short8 pf[2];
            #pragma unroll
            for (int mt = 0; mt < 2; ++mt)
                pf[mt] = *(const short8*)(psb + mt * 2048 + k2l * 1024 + rofs);
            __builtin_amdgcn_s_setprio(1);
            #pragma unroll
            for (int mt = 0; mt < 2; ++mt) {
                u[mt][0] = MFMA(pf[mt], gf[0][k2l], u[mt][0]);
                u[mt][1] = MFMA(pf[mt], gf[1][k2l], u[mt][1]);
            }
            __builtin_amdgcn_s_setprio(0);
        }
        if (it < 63) {
            const int nit = it + 1;
            const unsigned short* gb = gXb +
                ((size_t)(nit >> 1) * 32 + (size_t)(2 * w) * 4 +
                 (size_t)(nit & 1) * 2) * FRAG + l * 8;
            #pragma unroll
            for (int j = 0; j < 2; ++j)
                #pragma unroll
                for (int k2l = 0; k2l < 2; ++k2l)
                    gf[j][k2l] = *(const short8*)(gb + (j * 4 + k2l) * FRAG);
        }
    }

    // ---- epilogue: fused cls head (32 rows) ----
    float* lpartf = (float*)smem;           // [4][32]  (aliases Ps buf0, dead)
    float* opartf = (float*)(smem + 512);   // [4][32]

    #pragma unroll
    for (int mt = 0; mt < 2; ++mt) {
        lsum[mt] += __shfl_xor(lsum[mt], 16);
        lsum[mt] += __shfl_xor(lsum[mt], 32);
    }
    if (lq == 0) {
        #pragma unroll
        for (int mt = 0; mt < 2; ++mt)
            lpartf[w * 32 + mt * 16 + lm] = lsum[mt];
    }

    floatx4 hacc[2][2];
    {
        const float rs = RS_C;
        #pragma unroll
        for (int j = 0; j < 2; ++j) {
            int o = w * 32 + j * 16 + lm;
            short8 wf[4];
            #pragma unroll
            for (int ks = 0; ks < 4; ++ks) {
                const float* wp = w1 + (size_t)o * (2 * NC) + NC + ks * 32 + lq * 8;
                S8U t;
                t.u2[0] = make_uint2(pack2bf(wp[0] * rs, wp[1] * rs),
                                     pack2bf(wp[2] * rs, wp[3] * rs));
                t.u2[1] = make_uint2(pack2bf(wp[4] * rs, wp[5] * rs),
                                     pack2bf(wp[6] * rs, wp[7] * rs));
                wf[ks] = t.v;
            }
            #pragma unroll
            for (int mt = 0; mt < 2; ++mt) {
                floatx4 a = {0.f, 0.f, 0.f, 0.f};
                #pragma unroll
                for (int ks = 0; ks < 4; ++ks)
                    a = MFMA(qf[mt][ks], wf[ks], a);
                hacc[mt][j] = a;
            }
        }
    }
    __syncthreads();   // lpart visible

    float Abn[2], Dbn[2], W2[2];
    #pragma unroll
    for (int j = 0; j < 2; ++j) {
        int o = w * 32 + j * 16 + lm;
        float Ar = gammav[o] * rsqrtf(rvarv[o] + 1e-5f);
        Abn[j] = Ar;
        Dbn[j] = (b1v[o] - rmeanv[o]) * Ar + betav[o];
        W2[j]  = w2v[o];
    }
    float av[8];
    #pragma unroll
    for (int mt = 0; mt < 2; ++mt) {
        float4 L0 = *(const float4*)&lpartf[0 * 32 + mt * 16 + lq * 4];
        float4 L1 = *(const float4*)&lpartf[1 * 32 + mt * 16 + lq * 4];
        float4 L2 = *(const float4*)&lpartf[2 * 32 + mt * 16 + lq * 4];
        float4 L3 = *(const float4*)&lpartf[3 * 32 + mt * 16 + lq * 4];
        float4 Lt;
        Lt.x = (L0.x + L1.x) + (L2.x + L3.x);
        Lt.y = (L0.y + L1.y) + (L2.y + L3.y);
        Lt.z = (L0.z + L1.z) + (L2.z + L3.z);
        Lt.w = (L0.w + L1.w) + (L2.w + L3.w);
        #pragma unroll
        for (int r = 0; r < 4; ++r) {
            float rl = 1.f / ((const float*)&Lt)[r];
            float t0 = Abn[0] * (u[mt][0][r] * rl + hacc[mt][0][r]) + Dbn[0];
            float t1 = Abn[1] * (u[mt][1][r] * rl + hacc[mt][1][r]) + Dbn[1];
            t0 = t0 >= 0.f ? t0 : 0.01f * t0;
            t1 = t1 >= 0.f ? t1 : 0.01f * t1;
            av[mt * 4 + r] = W2[0] * t0 + W2[1] * t1;
        }
    }
    #pragma unroll
    for (int i = 0; i < 8; ++i) {
        av[i] += __shfl_xor(av[i], 1);
        av[i] += __shfl_xor(av[i], 2);
        av[i] += __shfl_xor(av[i], 4);
        av[i] += __shfl_xor(av[i], 8);
    }
    if (lm == 0) {
        #pragma unroll
        for (int mt = 0; mt < 2; ++mt)
            #pragma unroll
            for (int r = 0; r < 4; ++r)
                opartf[w * 32 + mt * 16 + lq * 4 + r] = av[mt * 4 + r];
    }
    __syncthreads();
    if (tid < 32)
        out[(size_t)b * NM + m0 + tid] =
            b2v[0] + opartf[tid] + opartf[32 + tid] +
            opartf[64 + tid] + opartf[96 + tid];
}

extern "C" void kernel_launch(void* const* d_in, const int* in_sizes, int n_in,
                              void* d_out, int out_size, void* d_ws, size_t ws_size,
                              hipStream_t stream) {
    const float* f     = (const float*)d_in[0];
    const float* w1    = (const float*)d_in[1];
    const float* b1    = (const float*)d_in[2];
    const float* gamma = (const float*)d_in[3];
    const float* beta  = (const float*)d_in[4];
    const float* rmean = (const float*)d_in[5];
    const float* rvar  = (const float*)d_in[6];
    const float* w2    = (const float*)d_in[7];
    const float* b2    = (const float*)d_in[8];
    float* out = (float*)d_out;

    unsigned short* fX = (unsigned short*)d_ws;              // 8 MB bf16 frag-order
    unsigned short* gX = fX + (size_t)NB * NM * NC;          // 8 MB bf16 frag-order

    hipLaunchKernelGGL(k_prep_f, dim3(512), dim3(256), 0, stream, f, fX);
    hipLaunchKernelGGL(k_prep_g, dim3(256), dim3(256), 0, stream, fX, w1, gX);
    hipLaunchKernelGGL(k_attn,   dim3(1024), dim3(256), 0, stream,
                       fX, gX, w1, b1, gamma, beta, rmean, rvar, w2, b2, out);
}

// Round 6
// 153.944 us; speedup vs baseline: 2.6207x; 1.1500x over previous
//
#include <hip/hip_runtime.h>

#define NB 8
#define NC 128
#define NM 4096
#define FRAG 512   // shorts per (tile,ks) fragment block: 64 lanes x 8

typedef __attribute__((ext_vector_type(8))) short short8;
typedef __attribute__((ext_vector_type(4))) float floatx4;

#define MFMA(a, b, c) __builtin_amdgcn_mfma_f32_16x16x32_bf16(a, b, c, 0, 0, 0)
#define EXP2F(x) __builtin_amdgcn_exp2f(x)

union S8U { short8 v; uint2 u2[2]; };

__device__ __forceinline__ unsigned pack2bf(float a, float b) {
    unsigned ua = __float_as_uint(a);
    unsigned ub = __float_as_uint(b);
    ua += 0x7fffu + ((ua >> 16) & 1u);
    ub += 0x7fffu + ((ub >> 16) & 1u);
    return (ua >> 16) | (ub & 0xffff0000u);
}

// Single-instruction packed f32->bf16 (RNE), same rounding as pack2bf.
__device__ __forceinline__ unsigned cvt_pk_bf16(float a, float b) {
    unsigned r;
    asm("v_cvt_pk_bf16_f32 %0, %1, %2" : "=v"(r) : "v"(a), "v"(b));
    return r;
}

// QK softmax scale folded into fX: sqrt(2^-3.5 * log2(e)); RS = 1/SF.
__constant__ float SF_C = 0.35712442f;
__constant__ float RS_C = 2.8001530f;

// ---------------------------------------------------------------------------
// Fragment-order layouts (one contiguous 1024B chunk per wave fragment load):
//   fX[b][mt(256)][ks(4)][lane(64)][8] : lane l=(lq*16+lm) holds
//       f-row (mt*16+lm), cols ks*32+lq*8..+7, scaled by SF, bf16.
//   gX[b][nblk(32)][ot(8)][k2(4)][lane(64)][8] : lane l holds
//       g-row o=ot*16+lm, cols n=nblk*128+k2*32+lq*8..+7, bf16.
// ---------------------------------------------------------------------------

// P1: fX from f (transpose + scale + bf16 + fragment order)
__global__ __launch_bounds__(256) void k_prep_f(
    const float* __restrict__ f, unsigned short* __restrict__ fX)
{
    __shared__ float Ls[128][65];
    const int tid = threadIdx.x;
    const int b   = blockIdx.x & 7;
    const int m0  = (blockIdx.x >> 3) * 64;
    const float* fb = f + (size_t)b * NC * NM;
    #pragma unroll
    for (int k = 0; k < 32; ++k) {
        int idx = tid + k * 256;
        int c = idx >> 6, mm = idx & 63;
        Ls[c][mm] = fb[(size_t)c * NM + m0 + mm];
    }
    __syncthreads();
    const float sf = SF_C;
    const int m  = tid >> 2;
    const int ks = tid & 3;
    const int ch = ks * 32;
    unsigned pk[16];
    #pragma unroll
    for (int i = 0; i < 16; ++i)
        pk[i] = pack2bf(Ls[ch + 2 * i][m] * sf, Ls[ch + 2 * i + 1][m] * sf);
    const int Mg  = m0 + m;
    const int mt  = Mg >> 4;
    const int lmm = Mg & 15;
    unsigned short* dst = fX + ((size_t)b * 256 + mt) * 4 * FRAG + ks * FRAG;
    #pragma unroll
    for (int q = 0; q < 4; ++q)
        *(uint4*)(dst + (q * 16 + lmm) * 8) =
            make_uint4(pk[4 * q], pk[4 * q + 1], pk[4 * q + 2], pk[4 * q + 3]);
}

// ---------------------------------------------------------------------------
// P2 (MFMA): gX = bf16( (w1a*RS) . fX ) in fragment order.
// grid 256 = b(8) x nblk(32); 4 waves; wave wv owns ot = 2wv, 2wv+1.
// ---------------------------------------------------------------------------
__global__ __launch_bounds__(256) void k_prep_g(
    const unsigned short* __restrict__ fX, const float* __restrict__ w1,
    unsigned short* __restrict__ gX)
{
    __shared__ unsigned short gt[128][136];   // [o][n-local]
    const int tid = threadIdx.x;
    const int wv  = tid >> 6;
    const int l   = tid & 63;
    const int lm  = l & 15;
    const int lq  = l >> 4;
    const int b    = blockIdx.x & 7;
    const int nblk = blockIdx.x >> 3;

    const float rs = RS_C;

    short8 wf2[2][4];
    #pragma unroll
    for (int j = 0; j < 2; ++j) {
        const int o = (wv * 2 + j) * 16 + lm;
        #pragma unroll
        for (int ks = 0; ks < 4; ++ks) {
            const float* wp = w1 + (size_t)o * (2 * NC) + ks * 32 + lq * 8;
            S8U t;
            t.u2[0] = make_uint2(pack2bf(wp[0] * rs, wp[1] * rs),
                                 pack2bf(wp[2] * rs, wp[3] * rs));
            t.u2[1] = make_uint2(pack2bf(wp[4] * rs, wp[5] * rs),
                                 pack2bf(wp[6] * rs, wp[7] * rs));
            wf2[j][ks] = t.v;
        }
    }

    const unsigned short* fXb = fX + (size_t)b * NM * NC;
    #pragma unroll 2
    for (int nt = 0; nt < 8; ++nt) {
        short8 af[4];
        #pragma unroll
        for (int ks = 0; ks < 4; ++ks)
            af[ks] = *(const short8*)
                (fXb + (size_t)(nblk * 8 + nt) * 4 * FRAG + ks * FRAG + l * 8);
        #pragma unroll
        for (int j = 0; j < 2; ++j) {
            floatx4 D = {0.f, 0.f, 0.f, 0.f};
            #pragma unroll
            for (int ks = 0; ks < 4; ++ks)
                D = MFMA(af[ks], wf2[j][ks], D);
            *(uint2*)&gt[(wv * 2 + j) * 16 + lm][nt * 16 + lq * 4] =
                make_uint2(pack2bf(D[0], D[1]), pack2bf(D[2], D[3]));
        }
    }
    __syncthreads();

    #pragma unroll
    for (int j = 0; j < 2; ++j) {
        const int ot = wv * 2 + j;
        #pragma unroll
        for (int k2 = 0; k2 < 4; ++k2) {
            uint4 v = *(const uint4*)&gt[ot * 16 + lm][k2 * 32 + lq * 8];
            *(uint4*)(gX + (((size_t)b * 32 + nblk) * 8 + ot) * 4 * FRAG
                      + k2 * FRAG + l * 8) = v;
        }
    }
}

// ---------------------------------------------------------------------------
// Main: MFMA flash attention + fused cls head. Round-1 geometry (64 rows,
// TN=128/iter, 4 waves, grid 512) with a PV-LAG pipeline: iter it computes
// QK(it) -> writes Ps[it&1], then PV(it-1) reading Ps[(it-1)&1] -- data
// ready since the PREVIOUS barrier, so the ds_read overlaps the QK MFMAs
// and the serial write->barrier->read->PV chain leaves the critical path.
// One barrier per iter (same hazard guarantees); gf register-ping-ponged
// via 2x-unrolled loop with static names; epilogue drains PV(31).
// ---------------------------------------------------------------------------
__global__ __launch_bounds__(256, 2) void k_attn(
    const unsigned short* __restrict__ fX,
    const unsigned short* __restrict__ gX,
    const float* __restrict__ w1,
    const float* __restrict__ b1v, const float* __restrict__ gammav,
    const float* __restrict__ betav, const float* __restrict__ rmeanv,
    const float* __restrict__ rvarv, const float* __restrict__ w2v,
    const float* __restrict__ b2v, float* __restrict__ out)
{
    __shared__ __align__(16) char Ps[2][16384];
    __shared__ float lpart[4][64];
    __shared__ float opart[4][64];

    const int tid = threadIdx.x;
    const int w   = tid >> 6;
    const int l   = tid & 63;
    const int lm  = l & 15;
    const int lq  = l >> 4;
    const int b   = blockIdx.x & 7;
    const int m0  = (blockIdx.x >> 3) * 64;

    // --- Ps addressing (fragment order + XOR swizzle), per-lane constant ---
    const int lq0 = lq & 1;
    const int lq1 = lq >> 1;
    const int lm3 = lm >> 3;
    const unsigned Xsw = (unsigned)(((lq1 << 1) | lm3) << 4);
    const unsigned wofsA =
        ((((unsigned)(w >> 1) * 4 * 16) + ((unsigned)(2 * (w & 1) + lq1) * 16)
          + (unsigned)lm) * 16 + (unsigned)(8 * lq0)) ^ Xsw;
    const unsigned rofs = ((unsigned)l * 16) ^ ((((unsigned)l >> 3) & 3u) << 4);

    const unsigned short* fXb = fX + (size_t)b * NM * NC;
    const unsigned short* gXb = gX + (size_t)b * NC * NM;

    short8 qf[4][4];
    {
        const int qt0 = m0 >> 4;
        #pragma unroll
        for (int mt = 0; mt < 4; ++mt)
            #pragma unroll
            for (int ks = 0; ks < 4; ++ks)
                qf[mt][ks] = *(const short8*)
                    (fXb + (size_t)(qt0 + mt) * 4 * FRAG + ks * FRAG + l * 8);
    }

    const unsigned short* kpA = fXb + (size_t)w * 4 * FRAG + l * 8;
    const unsigned short* kpB = fXb + (size_t)(4 + w) * 4 * FRAG + l * 8;
    const unsigned short* gp0 = gXb + (size_t)(2 * w) * 4 * FRAG + l * 8;
    const unsigned short* gp1 = gXb + (size_t)(2 * w + 1) * 4 * FRAG + l * 8;

    short8 kfA[4], kfB[4];
    short8 gA0[4], gA1[4], gB0[4], gB1[4];
    #pragma unroll
    for (int ks = 0; ks < 4; ++ks) {
        kfA[ks] = *(const short8*)(kpA + ks * FRAG);
        kfB[ks] = *(const short8*)(kpB + ks * FRAG);
    }
    #pragma unroll
    for (int k2 = 0; k2 < 4; ++k2) {           // gA = gf(0)
        gA0[k2] = *(const short8*)(gp0 + k2 * FRAG);
        gA1[k2] = *(const short8*)(gp1 + k2 * FRAG);
    }

    floatx4 u[4][2];
    float lsum[4] = {0.f, 0.f, 0.f, 0.f};
    #pragma unroll
    for (int mt = 0; mt < 4; ++mt) {
        u[mt][0] = (floatx4){0.f, 0.f, 0.f, 0.f};
        u[mt][1] = (floatx4){0.f, 0.f, 0.f, 0.f};
    }

    // ---- prologue: it = 0 -> QK(0), exp2, write Ps[0], barrier ----
    {
        floatx4 svA[4], svB[4];
        __builtin_amdgcn_s_setprio(1);
        #pragma unroll
        for (int mt = 0; mt < 4; ++mt) {
            floatx4 a = {-24.f, -24.f, -24.f, -24.f};
            floatx4 bb = {-24.f, -24.f, -24.f, -24.f};
            #pragma unroll
            for (int ks = 0; ks < 4; ++ks) {
                a  = MFMA(kfA[ks], qf[mt][ks], a);
                bb = MFMA(kfB[ks], qf[mt][ks], bb);
            }
            svA[mt] = a; svB[mt] = bb;
        }
        __builtin_amdgcn_s_setprio(0);
        kpA += 8 * 4 * FRAG; kpB += 8 * 4 * FRAG;   // kf -> kf(1)
        #pragma unroll
        for (int ks = 0; ks < 4; ++ks) {
            kfA[ks] = *(const short8*)(kpA + ks * FRAG);
            kfB[ks] = *(const short8*)(kpB + ks * FRAG);
        }
        char* psb = Ps[0];
        #pragma unroll
        for (int mt = 0; mt < 4; ++mt) {
            float pA0 = EXP2F(svA[mt][0]);
            float pA1 = EXP2F(svA[mt][1]);
            float pA2 = EXP2F(svA[mt][2]);
            float pA3 = EXP2F(svA[mt][3]);
            float pB0 = EXP2F(svB[mt][0]);
            float pB1 = EXP2F(svB[mt][1]);
            float pB2 = EXP2F(svB[mt][2]);
            float pB3 = EXP2F(svB[mt][3]);
            lsum[mt] += ((pA0 + pA1) + (pA2 + pA3)) +
                        ((pB0 + pB1) + (pB2 + pB3));
            *(uint2*)(psb + mt * 4096 + wofsA) =
                make_uint2(cvt_pk_bf16(pA0, pA1), cvt_pk_bf16(pA2, pA3));
            *(uint2*)(psb + mt * 4096 + wofsA + 2048) =
                make_uint2(cvt_pk_bf16(pB0, pB1), cvt_pk_bf16(pB2, pB3));
        }
        __syncthreads();
    }

    // Body for iter IT (1..31): QK(IT) -> Ps[psW]; PV(IT-1) from Ps[psR]
    // with gC; prefetch kf(IT+1) (if LOADK) and gf(IT) into gN.
    auto body = [&](char* psW, char* psR,
                    short8 (&gC0)[4], short8 (&gC1)[4],
                    short8 (&gN0)[4], short8 (&gN1)[4], bool loadK) {
        floatx4 svA[4], svB[4];
        __builtin_amdgcn_s_setprio(1);
        #pragma unroll
        for (int mt = 0; mt < 4; ++mt) {
            floatx4 a = {-24.f, -24.f, -24.f, -24.f};
            floatx4 bb = {-24.f, -24.f, -24.f, -24.f};
            #pragma unroll
            for (int ks = 0; ks < 4; ++ks) {
                a  = MFMA(kfA[ks], qf[mt][ks], a);
                bb = MFMA(kfB[ks], qf[mt][ks], bb);
            }
            svA[mt] = a; svB[mt] = bb;
        }
        __builtin_amdgcn_s_setprio(0);
        if (loadK) {
            kpA += 8 * 4 * FRAG; kpB += 8 * 4 * FRAG;
            #pragma unroll
            for (int ks = 0; ks < 4; ++ks) {
                kfA[ks] = *(const short8*)(kpA + ks * FRAG);
                kfB[ks] = *(const short8*)(kpB + ks * FRAG);
            }
        }
        gp0 += 8 * 4 * FRAG; gp1 += 8 * 4 * FRAG;   // gf(IT)
        #pragma unroll
        for (int k2 = 0; k2 < 4; ++k2) {
            gN0[k2] = *(const short8*)(gp0 + k2 * FRAG);
            gN1[k2] = *(const short8*)(gp1 + k2 * FRAG);
        }
        #pragma unroll
        for (int mt = 0; mt < 4; ++mt) {
            float pA0 = EXP2F(svA[mt][0]);
            float pA1 = EXP2F(svA[mt][1]);
            float pA2 = EXP2F(svA[mt][2]);
            float pA3 = EXP2F(svA[mt][3]);
            float pB0 = EXP2F(svB[mt][0]);
            float pB1 = EXP2F(svB[mt][1]);
            float pB2 = EXP2F(svB[mt][2]);
            float pB3 = EXP2F(svB[mt][3]);
            lsum[mt] += ((pA0 + pA1) + (pA2 + pA3)) +
                        ((pB0 + pB1) + (pB2 + pB3));
            *(uint2*)(psW + mt * 4096 + wofsA) =
                make_uint2(cvt_pk_bf16(pA0, pA1), cvt_pk_bf16(pA2, pA3));
            *(uint2*)(psW + mt * 4096 + wofsA + 2048) =
                make_uint2(cvt_pk_bf16(pB0, pB1), cvt_pk_bf16(pB2, pB3));
        }
        // PV(IT-1): Ps[psR] ready since the previous barrier.
        #pragma unroll
        for (int k2 = 0; k2 < 4; ++k2) {
            short8 pf[4];
            #pragma unroll
            for (int mt = 0; mt < 4; ++mt)
                pf[mt] = *(const short8*)(psR + mt * 4096 + k2 * 1024 + rofs);
            __builtin_amdgcn_s_setprio(1);
            #pragma unroll
            for (int mt = 0; mt < 4; ++mt) {
                u[mt][0] = MFMA(pf[mt], gC0[k2], u[mt][0]);
                u[mt][1] = MFMA(pf[mt], gC1[k2], u[mt][1]);
            }
            __builtin_amdgcn_s_setprio(0);
        }
        __syncthreads();
    };

    // it = 1..30 (15 odd/even pairs), then it = 31 (no kf prefetch).
    for (int i = 0; i < 15; ++i) {
        body(Ps[1], Ps[0], gA0, gA1, gB0, gB1, true);   // odd it: C=gA, N=gB
        body(Ps[0], Ps[1], gB0, gB1, gA0, gA1, true);   // even it: C=gB, N=gA
    }
    body(Ps[1], Ps[0], gA0, gA1, gB0, gB1, false);      // it=31: gB <- gf(31)

    // ---- drain: PV(31) from Ps[1] with gB ----
    #pragma unroll
    for (int k2 = 0; k2 < 4; ++k2) {
        short8 pf[4];
        #pragma unroll
        for (int mt = 0; mt < 4; ++mt)
            pf[mt] = *(const short8*)(Ps[1] + mt * 4096 + k2 * 1024 + rofs);
        __builtin_amdgcn_s_setprio(1);
        #pragma unroll
        for (int mt = 0; mt < 4; ++mt) {
            u[mt][0] = MFMA(pf[mt], gB0[k2], u[mt][0]);
            u[mt][1] = MFMA(pf[mt], gB1[k2], u[mt][1]);
        }
        __builtin_amdgcn_s_setprio(0);
    }

    #pragma unroll
    for (int mt = 0; mt < 4; ++mt) {
        lsum[mt] += __shfl_xor(lsum[mt], 16);
        lsum[mt] += __shfl_xor(lsum[mt], 32);
    }
    if (lq == 0) {
        #pragma unroll
        for (int mt = 0; mt < 4; ++mt)
            lpart[w][mt * 16 + lm] = lsum[mt];
    }

    floatx4 hacc[4][2];
    {
        const float rs = RS_C;
        #pragma unroll
        for (int j = 0; j < 2; ++j) {
            int o = w * 32 + j * 16 + lm;
            short8 wf[4];
            #pragma unroll
            for (int ks = 0; ks < 4; ++ks) {
                const float* wp = w1 + (size_t)o * (2 * NC) + NC + ks * 32 + lq * 8;
                S8U t;
                t.u2[0] = make_uint2(pack2bf(wp[0] * rs, wp[1] * rs),
                                     pack2bf(wp[2] * rs, wp[3] * rs));
                t.u2[1] = make_uint2(pack2bf(wp[4] * rs, wp[5] * rs),
                                     pack2bf(wp[6] * rs, wp[7] * rs));
                wf[ks] = t.v;
            }
            #pragma unroll
            for (int mt = 0; mt < 4; ++mt) {
                floatx4 a = {0.f, 0.f, 0.f, 0.f};
                #pragma unroll
                for (int ks = 0; ks < 4; ++ks)
                    a = MFMA(qf[mt][ks], wf[ks], a);
                hacc[mt][j] = a;
            }
        }
    }
    __syncthreads();

    float Abn[2], Dbn[2], W2[2];
    #pragma unroll
    for (int j = 0; j < 2; ++j) {
        int o = w * 32 + j * 16 + lm;
        float Ar = gammav[o] * rsqrtf(rvarv[o] + 1e-5f);
        Abn[j] = Ar;
        Dbn[j] = (b1v[o] - rmeanv[o]) * Ar + betav[o];
        W2[j]  = w2v[o];
    }
    float av[16];
    #pragma unroll
    for (int mt = 0; mt < 4; ++mt) {
        float4 L0 = *(const float4*)&lpart[0][mt * 16 + lq * 4];
        float4 L1 = *(const float4*)&lpart[1][mt * 16 + lq * 4];
        float4 L2 = *(const float4*)&lpart[2][mt * 16 + lq * 4];
        float4 L3 = *(const float4*)&lpart[3][mt * 16 + lq * 4];
        float4 Lt;
        Lt.x = (L0.x + L1.x) + (L2.x + L3.x);
        Lt.y = (L0.y + L1.y) + (L2.y + L3.y);
        Lt.z = (L0.z + L1.z) + (L2.z + L3.z);
        Lt.w = (L0.w + L1.w) + (L2.w + L3.w);
        #pragma unroll
        for (int r = 0; r < 4; ++r) {
            float rl = 1.f / ((const float*)&Lt)[r];
            float t0 = Abn[0] * (u[mt][0][r] * rl + hacc[mt][0][r]) + Dbn[0];
            float t1 = Abn[1] * (u[mt][1][r] * rl + hacc[mt][1][r]) + Dbn[1];
            t0 = t0 >= 0.f ? t0 : 0.01f * t0;
            t1 = t1 >= 0.f ? t1 : 0.01f * t1;
            av[mt * 4 + r] = W2[0] * t0 + W2[1] * t1;
        }
    }
    #pragma unroll
    for (int i = 0; i < 16; ++i) {
        av[i] += __shfl_xor(av[i], 1);
        av[i] += __shfl_xor(av[i], 2);
        av[i] += __shfl_xor(av[i], 4);
        av[i] += __shfl_xor(av[i], 8);
    }
    if (lm == 0) {
        #pragma unroll
        for (int mt = 0; mt < 4; ++mt)
            #pragma unroll
            for (int r = 0; r < 4; ++r)
                opart[w][mt * 16 + lq * 4 + r] = av[mt * 4 + r];
    }
    __syncthreads();
    if (tid < 64)
        out[(size_t)b * NM + m0 + tid] =
            b2v[0] + opart[0][tid] + opart[1][tid] + opart[2][tid] + opart[3][tid];
}

extern "C" void kernel_launch(void* const* d_in, const int* in_sizes, int n_in,
                              void* d_out, int out_size, void* d_ws, size_t ws_size,
                              hipStream_t stream) {
    const float* f     = (const float*)d_in[0];
    const float* w1    = (const float*)d_in[1];
    const float* b1    = (const float*)d_in[2];
    const float* gamma = (const float*)d_in[3];
    const float* beta  = (const float*)d_in[4];
    const float* rmean = (const float*)d_in[5];
    const float* rvar  = (const float*)d_in[6];
    const float* w2    = (const float*)d_in[7];
    const float* b2    = (const float*)d_in[8];
    float* out = (float*)d_out;

    unsigned short* fX = (unsigned short*)d_ws;              // 8 MB bf16 frag-order
    unsigned short* gX = fX + (size_t)NB * NM * NC;          // 8 MB bf16 frag-order

    hipLaunchKernelGGL(k_prep_f, dim3(512), dim3(256), 0, stream, f, fX);
    hipLaunchKernelGGL(k_prep_g, dim3(256), dim3(256), 0, stream, fX, w1, gX);
    hipLaunchKernelGGL(k_attn,   dim3(512), dim3(256), 0, stream,
                       fX, gX, w1, b1, gamma, beta, rmean, rvar, w2, b2, out);
}

// Round 7
// 152.557 us; speedup vs baseline: 2.6445x; 1.0091x over previous
//
#include <hip/hip_runtime.h>

#define NB 8
#define NC 128
#define NM 4096
#define FRAG 512   // shorts per (tile,ks) fragment block: 64 lanes x 8

typedef __attribute__((ext_vector_type(8))) short short8;
typedef __attribute__((ext_vector_type(4))) float floatx4;

#define MFMA(a, b, c) __builtin_amdgcn_mfma_f32_16x16x32_bf16(a, b, c, 0, 0, 0)
#define EXP2F(x) __builtin_amdgcn_exp2f(x)

// LDS-only barrier: order Ps ds_writes (lgkmcnt) across waves WITHOUT
// draining outstanding global register loads (vmcnt) -- kf/gf prefetches
// stay in flight across the barrier (T4 counted-vmcnt idiom).
#define LDS_BARRIER() do {                                       \
    asm volatile("s_waitcnt lgkmcnt(0)" ::: "memory");           \
    __builtin_amdgcn_s_barrier();                                \
} while (0)

union S8U { short8 v; uint2 u2[2]; };

__device__ __forceinline__ unsigned pack2bf(float a, float b) {
    unsigned ua = __float_as_uint(a);
    unsigned ub = __float_as_uint(b);
    ua += 0x7fffu + ((ua >> 16) & 1u);
    ub += 0x7fffu + ((ub >> 16) & 1u);
    return (ua >> 16) | (ub & 0xffff0000u);
}

// Single-instruction packed f32->bf16 (RNE), same rounding as pack2bf.
__device__ __forceinline__ unsigned cvt_pk_bf16(float a, float b) {
    unsigned r;
    asm("v_cvt_pk_bf16_f32 %0, %1, %2" : "=v"(r) : "v"(a), "v"(b));
    return r;
}

// QK softmax scale folded into fX: sqrt(2^-3.5 * log2(e)); RS = 1/SF.
__constant__ float SF_C = 0.35712442f;
__constant__ float RS_C = 2.8001530f;

// ---------------------------------------------------------------------------
// Fragment-order layouts (one contiguous 1024B chunk per wave fragment load):
//   fX[b][mt(256)][ks(4)][lane(64)][8] : lane l=(lq*16+lm) holds
//       f-row (mt*16+lm), cols ks*32+lq*8..+7, scaled by SF, bf16.
//   gX[b][nblk(32)][ot(8)][k2(4)][lane(64)][8] : lane l holds
//       g-row o=ot*16+lm, cols n=nblk*128+k2*32+lq*8..+7, bf16.
// ---------------------------------------------------------------------------

// P1: fX from f (transpose + scale + bf16 + fragment order)
__global__ __launch_bounds__(256) void k_prep_f(
    const float* __restrict__ f, unsigned short* __restrict__ fX)
{
    __shared__ float Ls[128][65];
    const int tid = threadIdx.x;
    const int b   = blockIdx.x & 7;
    const int m0  = (blockIdx.x >> 3) * 64;
    const float* fb = f + (size_t)b * NC * NM;
    #pragma unroll
    for (int k = 0; k < 32; ++k) {
        int idx = tid + k * 256;
        int c = idx >> 6, mm = idx & 63;
        Ls[c][mm] = fb[(size_t)c * NM + m0 + mm];
    }
    __syncthreads();
    const float sf = SF_C;
    const int m  = tid >> 2;
    const int ks = tid & 3;
    const int ch = ks * 32;
    unsigned pk[16];
    #pragma unroll
    for (int i = 0; i < 16; ++i)
        pk[i] = pack2bf(Ls[ch + 2 * i][m] * sf, Ls[ch + 2 * i + 1][m] * sf);
    const int Mg  = m0 + m;
    const int mt  = Mg >> 4;
    const int lmm = Mg & 15;
    unsigned short* dst = fX + ((size_t)b * 256 + mt) * 4 * FRAG + ks * FRAG;
    #pragma unroll
    for (int q = 0; q < 4; ++q)
        *(uint4*)(dst + (q * 16 + lmm) * 8) =
            make_uint4(pk[4 * q], pk[4 * q + 1], pk[4 * q + 2], pk[4 * q + 3]);
}

// ---------------------------------------------------------------------------
// P2 (MFMA): gX = bf16( (w1a*RS) . fX ) in fragment order.
// grid 256 = b(8) x nblk(32); 4 waves; wave wv owns ot = 2wv, 2wv+1.
// ---------------------------------------------------------------------------
__global__ __launch_bounds__(256) void k_prep_g(
    const unsigned short* __restrict__ fX, const float* __restrict__ w1,
    unsigned short* __restrict__ gX)
{
    __shared__ unsigned short gt[128][136];   // [o][n-local]
    const int tid = threadIdx.x;
    const int wv  = tid >> 6;
    const int l   = tid & 63;
    const int lm  = l & 15;
    const int lq  = l >> 4;
    const int b    = blockIdx.x & 7;
    const int nblk = blockIdx.x >> 3;

    const float rs = RS_C;

    short8 wf2[2][4];
    #pragma unroll
    for (int j = 0; j < 2; ++j) {
        const int o = (wv * 2 + j) * 16 + lm;
        #pragma unroll
        for (int ks = 0; ks < 4; ++ks) {
            const float* wp = w1 + (size_t)o * (2 * NC) + ks * 32 + lq * 8;
            S8U t;
            t.u2[0] = make_uint2(pack2bf(wp[0] * rs, wp[1] * rs),
                                 pack2bf(wp[2] * rs, wp[3] * rs));
            t.u2[1] = make_uint2(pack2bf(wp[4] * rs, wp[5] * rs),
                                 pack2bf(wp[6] * rs, wp[7] * rs));
            wf2[j][ks] = t.v;
        }
    }

    const unsigned short* fXb = fX + (size_t)b * NM * NC;
    #pragma unroll 2
    for (int nt = 0; nt < 8; ++nt) {
        short8 af[4];
        #pragma unroll
        for (int ks = 0; ks < 4; ++ks)
            af[ks] = *(const short8*)
                (fXb + (size_t)(nblk * 8 + nt) * 4 * FRAG + ks * FRAG + l * 8);
        #pragma unroll
        for (int j = 0; j < 2; ++j) {
            floatx4 D = {0.f, 0.f, 0.f, 0.f};
            #pragma unroll
            for (int ks = 0; ks < 4; ++ks)
                D = MFMA(af[ks], wf2[j][ks], D);
            *(uint2*)&gt[(wv * 2 + j) * 16 + lm][nt * 16 + lq * 4] =
                make_uint2(pack2bf(D[0], D[1]), pack2bf(D[2], D[3]));
        }
    }
    __syncthreads();

    #pragma unroll
    for (int j = 0; j < 2; ++j) {
        const int ot = wv * 2 + j;
        #pragma unroll
        for (int k2 = 0; k2 < 4; ++k2) {
            uint4 v = *(const uint4*)&gt[ot * 16 + lm][k2 * 32 + lq * 8];
            *(uint4*)(gX + (((size_t)b * 32 + nblk) * 8 + ot) * 4 * FRAG
                      + k2 * FRAG + l * 8) = v;
        }
    }
}

// ---------------------------------------------------------------------------
// Main: MFMA flash attention + fused cls head. Round-6 PV-lag pipeline
// (QK(it) -> Ps[it&1]; PV(it-1) from Ps[(it-1)&1]; one barrier/iter) with
// the in-loop barrier changed to LDS-only (lgkmcnt(0) + raw s_barrier):
// kf/gf global register prefetches are no longer drained at each barrier
// and stay in flight across it. grid 512 = b(8) x mblock(64); 4 waves.
// ---------------------------------------------------------------------------
__global__ __launch_bounds__(256, 2) void k_attn(
    const unsigned short* __restrict__ fX,
    const unsigned short* __restrict__ gX,
    const float* __restrict__ w1,
    const float* __restrict__ b1v, const float* __restrict__ gammav,
    const float* __restrict__ betav, const float* __restrict__ rmeanv,
    const float* __restrict__ rvarv, const float* __restrict__ w2v,
    const float* __restrict__ b2v, float* __restrict__ out)
{
    __shared__ __align__(16) char Ps[2][16384];
    __shared__ float lpart[4][64];
    __shared__ float opart[4][64];

    const int tid = threadIdx.x;
    const int w   = tid >> 6;
    const int l   = tid & 63;
    const int lm  = l & 15;
    const int lq  = l >> 4;
    const int b   = blockIdx.x & 7;
    const int m0  = (blockIdx.x >> 3) * 64;

    // --- Ps addressing (fragment order + XOR swizzle), per-lane constant ---
    const int lq0 = lq & 1;
    const int lq1 = lq >> 1;
    const int lm3 = lm >> 3;
    const unsigned Xsw = (unsigned)(((lq1 << 1) | lm3) << 4);
    const unsigned wofsA =
        ((((unsigned)(w >> 1) * 4 * 16) + ((unsigned)(2 * (w & 1) + lq1) * 16)
          + (unsigned)lm) * 16 + (unsigned)(8 * lq0)) ^ Xsw;
    const unsigned rofs = ((unsigned)l * 16) ^ ((((unsigned)l >> 3) & 3u) << 4);

    const unsigned short* fXb = fX + (size_t)b * NM * NC;
    const unsigned short* gXb = gX + (size_t)b * NC * NM;

    short8 qf[4][4];
    {
        const int qt0 = m0 >> 4;
        #pragma unroll
        for (int mt = 0; mt < 4; ++mt)
            #pragma unroll
            for (int ks = 0; ks < 4; ++ks)
                qf[mt][ks] = *(const short8*)
                    (fXb + (size_t)(qt0 + mt) * 4 * FRAG + ks * FRAG + l * 8);
    }

    const unsigned short* kpA = fXb + (size_t)w * 4 * FRAG + l * 8;
    const unsigned short* kpB = fXb + (size_t)(4 + w) * 4 * FRAG + l * 8;
    const unsigned short* gp0 = gXb + (size_t)(2 * w) * 4 * FRAG + l * 8;
    const unsigned short* gp1 = gXb + (size_t)(2 * w + 1) * 4 * FRAG + l * 8;

    short8 kfA[4], kfB[4];
    short8 gA0[4], gA1[4], gB0[4], gB1[4];
    #pragma unroll
    for (int ks = 0; ks < 4; ++ks) {
        kfA[ks] = *(const short8*)(kpA + ks * FRAG);
        kfB[ks] = *(const short8*)(kpB + ks * FRAG);
    }
    #pragma unroll
    for (int k2 = 0; k2 < 4; ++k2) {           // gA = gf(0)
        gA0[k2] = *(const short8*)(gp0 + k2 * FRAG);
        gA1[k2] = *(const short8*)(gp1 + k2 * FRAG);
    }

    floatx4 u[4][2];
    float lsum[4] = {0.f, 0.f, 0.f, 0.f};
    #pragma unroll
    for (int mt = 0; mt < 4; ++mt) {
        u[mt][0] = (floatx4){0.f, 0.f, 0.f, 0.f};
        u[mt][1] = (floatx4){0.f, 0.f, 0.f, 0.f};
    }

    // ---- prologue: it = 0 -> QK(0), exp2, write Ps[0], barrier ----
    {
        floatx4 svA[4], svB[4];
        __builtin_amdgcn_s_setprio(1);
        #pragma unroll
        for (int mt = 0; mt < 4; ++mt) {
            floatx4 a = {-24.f, -24.f, -24.f, -24.f};
            floatx4 bb = {-24.f, -24.f, -24.f, -24.f};
            #pragma unroll
            for (int ks = 0; ks < 4; ++ks) {
                a  = MFMA(kfA[ks], qf[mt][ks], a);
                bb = MFMA(kfB[ks], qf[mt][ks], bb);
            }
            svA[mt] = a; svB[mt] = bb;
        }
        __builtin_amdgcn_s_setprio(0);
        kpA += 8 * 4 * FRAG; kpB += 8 * 4 * FRAG;   // kf -> kf(1)
        #pragma unroll
        for (int ks = 0; ks < 4; ++ks) {
            kfA[ks] = *(const short8*)(kpA + ks * FRAG);
            kfB[ks] = *(const short8*)(kpB + ks * FRAG);
        }
        char* psb = Ps[0];
        #pragma unroll
        for (int mt = 0; mt < 4; ++mt) {
            float pA0 = EXP2F(svA[mt][0]);
            float pA1 = EXP2F(svA[mt][1]);
            float pA2 = EXP2F(svA[mt][2]);
            float pA3 = EXP2F(svA[mt][3]);
            float pB0 = EXP2F(svB[mt][0]);
            float pB1 = EXP2F(svB[mt][1]);
            float pB2 = EXP2F(svB[mt][2]);
            float pB3 = EXP2F(svB[mt][3]);
            lsum[mt] += ((pA0 + pA1) + (pA2 + pA3)) +
                        ((pB0 + pB1) + (pB2 + pB3));
            *(uint2*)(psb + mt * 4096 + wofsA) =
                make_uint2(cvt_pk_bf16(pA0, pA1), cvt_pk_bf16(pA2, pA3));
            *(uint2*)(psb + mt * 4096 + wofsA + 2048) =
                make_uint2(cvt_pk_bf16(pB0, pB1), cvt_pk_bf16(pB2, pB3));
        }
        LDS_BARRIER();
    }

    // Body for iter IT (1..31): QK(IT) -> Ps[psW]; PV(IT-1) from Ps[psR]
    // with gC; prefetch kf(IT+1) (if LOADK) and gf(IT) into gN.
    auto body = [&](char* psW, char* psR,
                    short8 (&gC0)[4], short8 (&gC1)[4],
                    short8 (&gN0)[4], short8 (&gN1)[4], bool loadK) {
        floatx4 svA[4], svB[4];
        __builtin_amdgcn_s_setprio(1);
        #pragma unroll
        for (int mt = 0; mt < 4; ++mt) {
            floatx4 a = {-24.f, -24.f, -24.f, -24.f};
            floatx4 bb = {-24.f, -24.f, -24.f, -24.f};
            #pragma unroll
            for (int ks = 0; ks < 4; ++ks) {
                a  = MFMA(kfA[ks], qf[mt][ks], a);
                bb = MFMA(kfB[ks], qf[mt][ks], bb);
            }
            svA[mt] = a; svB[mt] = bb;
        }
        __builtin_amdgcn_s_setprio(0);
        if (loadK) {
            kpA += 8 * 4 * FRAG; kpB += 8 * 4 * FRAG;
            #pragma unroll
            for (int ks = 0; ks < 4; ++ks) {
                kfA[ks] = *(const short8*)(kpA + ks * FRAG);
                kfB[ks] = *(const short8*)(kpB + ks * FRAG);
            }
        }
        gp0 += 8 * 4 * FRAG; gp1 += 8 * 4 * FRAG;   // gf(IT)
        #pragma unroll
        for (int k2 = 0; k2 < 4; ++k2) {
            gN0[k2] = *(const short8*)(gp0 + k2 * FRAG);
            gN1[k2] = *(const short8*)(gp1 + k2 * FRAG);
        }
        #pragma unroll
        for (int mt = 0; mt < 4; ++mt) {
            float pA0 = EXP2F(svA[mt][0]);
            float pA1 = EXP2F(svA[mt][1]);
            float pA2 = EXP2F(svA[mt][2]);
            float pA3 = EXP2F(svA[mt][3]);
            float pB0 = EXP2F(svB[mt][0]);
            float pB1 = EXP2F(svB[mt][1]);
            float pB2 = EXP2F(svB[mt][2]);
            float pB3 = EXP2F(svB[mt][3]);
            lsum[mt] += ((pA0 + pA1) + (pA2 + pA3)) +
                        ((pB0 + pB1) + (pB2 + pB3));
            *(uint2*)(psW + mt * 4096 + wofsA) =
                make_uint2(cvt_pk_bf16(pA0, pA1), cvt_pk_bf16(pA2, pA3));
            *(uint2*)(psW + mt * 4096 + wofsA + 2048) =
                make_uint2(cvt_pk_bf16(pB0, pB1), cvt_pk_bf16(pB2, pB3));
        }
        // PV(IT-1): Ps[psR] ready since the previous barrier.
        #pragma unroll
        for (int k2 = 0; k2 < 4; ++k2) {
            short8 pf[4];
            #pragma unroll
            for (int mt = 0; mt < 4; ++mt)
                pf[mt] = *(const short8*)(psR + mt * 4096 + k2 * 1024 + rofs);
            __builtin_amdgcn_s_setprio(1);
            #pragma unroll
            for (int mt = 0; mt < 4; ++mt) {
                u[mt][0] = MFMA(pf[mt], gC0[k2], u[mt][0]);
                u[mt][1] = MFMA(pf[mt], gC1[k2], u[mt][1]);
            }
            __builtin_amdgcn_s_setprio(0);
        }
        LDS_BARRIER();
    };

    // it = 1..30 (15 odd/even pairs), then it = 31 (no kf prefetch).
    for (int i = 0; i < 15; ++i) {
        body(Ps[1], Ps[0], gA0, gA1, gB0, gB1, true);   // odd it: C=gA, N=gB
        body(Ps[0], Ps[1], gB0, gB1, gA0, gA1, true);   // even it: C=gB, N=gA
    }
    body(Ps[1], Ps[0], gA0, gA1, gB0, gB1, false);      // it=31: gB <- gf(31)

    // ---- drain: PV(31) from Ps[1] with gB ----
    #pragma unroll
    for (int k2 = 0; k2 < 4; ++k2) {
        short8 pf[4];
        #pragma unroll
        for (int mt = 0; mt < 4; ++mt)
            pf[mt] = *(const short8*)(Ps[1] + mt * 4096 + k2 * 1024 + rofs);
        __builtin_amdgcn_s_setprio(1);
        #pragma unroll
        for (int mt = 0; mt < 4; ++mt) {
            u[mt][0] = MFMA(pf[mt], gB0[k2], u[mt][0]);
            u[mt][1] = MFMA(pf[mt], gB1[k2], u[mt][1]);
        }
        __builtin_amdgcn_s_setprio(0);
    }

    #pragma unroll
    for (int mt = 0; mt < 4; ++mt) {
        lsum[mt] += __shfl_xor(lsum[mt], 16);
        lsum[mt] += __shfl_xor(lsum[mt], 32);
    }
    if (lq == 0) {
        #pragma unroll
        for (int mt = 0; mt < 4; ++mt)
            lpart[w][mt * 16 + lm] = lsum[mt];
    }

    floatx4 hacc[4][2];
    {
        const float rs = RS_C;
        #pragma unroll
        for (int j = 0; j < 2; ++j) {
            int o = w * 32 + j * 16 + lm;
            short8 wf[4];
            #pragma unroll
            for (int ks = 0; ks < 4; ++ks) {
                const float* wp = w1 + (size_t)o * (2 * NC) + NC + ks * 32 + lq * 8;
                S8U t;
                t.u2[0] = make_uint2(pack2bf(wp[0] * rs, wp[1] * rs),
                                     pack2bf(wp[2] * rs, wp[3] * rs));
                t.u2[1] = make_uint2(pack2bf(wp[4] * rs, wp[5] * rs),
                                     pack2bf(wp[6] * rs, wp[7] * rs));
                wf[ks] = t.v;
            }
            #pragma unroll
            for (int mt = 0; mt < 4; ++mt) {
                floatx4 a = {0.f, 0.f, 0.f, 0.f};
                #pragma unroll
                for (int ks = 0; ks < 4; ++ks)
                    a = MFMA(qf[mt][ks], wf[ks], a);
                hacc[mt][j] = a;
            }
        }
    }
    __syncthreads();

    float Abn[2], Dbn[2], W2[2];
    #pragma unroll
    for (int j = 0; j < 2; ++j) {
        int o = w * 32 + j * 16 + lm;
        float Ar = gammav[o] * rsqrtf(rvarv[o] + 1e-5f);
        Abn[j] = Ar;
        Dbn[j] = (b1v[o] - rmeanv[o]) * Ar + betav[o];
        W2[j]  = w2v[o];
    }
    float av[16];
    #pragma unroll
    for (int mt = 0; mt < 4; ++mt) {
        float4 L0 = *(const float4*)&lpart[0][mt * 16 + lq * 4];
        float4 L1 = *(const float4*)&lpart[1][mt * 16 + lq * 4];
        float4 L2 = *(const float4*)&lpart[2][mt * 16 + lq * 4];
        float4 L3 = *(const float4*)&lpart[3][mt * 16 + lq * 4];
        float4 Lt;
        Lt.x = (L0.x + L1.x) + (L2.x + L3.x);
        Lt.y = (L0.y + L1.y) + (L2.y + L3.y);
        Lt.z = (L0.z + L1.z) + (L2.z + L3.z);
        Lt.w = (L0.w + L1.w) + (L2.w + L3.w);
        #pragma unroll
        for (int r = 0; r < 4; ++r) {
            float rl = 1.f / ((const float*)&Lt)[r];
            float t0 = Abn[0] * (u[mt][0][r] * rl + hacc[mt][0][r]) + Dbn[0];
            float t1 = Abn[1] * (u[mt][1][r] * rl + hacc[mt][1][r]) + Dbn[1];
            t0 = t0 >= 0.f ? t0 : 0.01f * t0;
            t1 = t1 >= 0.f ? t1 : 0.01f * t1;
            av[mt * 4 + r] = W2[0] * t0 + W2[1] * t1;
        }
    }
    #pragma unroll
    for (int i = 0; i < 16; ++i) {
        av[i] += __shfl_xor(av[i], 1);
        av[i] += __shfl_xor(av[i], 2);
        av[i] += __shfl_xor(av[i], 4);
        av[i] += __shfl_xor(av[i], 8);
    }
    if (lm == 0) {
        #pragma unroll
        for (int mt = 0; mt < 4; ++mt)
            #pragma unroll
            for (int r = 0; r < 4; ++r)
                opart[w][mt * 16 + lq * 4 + r] = av[mt * 4 + r];
    }
    __syncthreads();
    if (tid < 64)
        out[(size_t)b * NM + m0 + tid] =
            b2v[0] + opart[0][tid] + opart[1][tid] + opart[2][tid] + opart[3][tid];
}

extern "C" void kernel_launch(void* const* d_in, const int* in_sizes, int n_in,
                              void* d_out, int out_size, void* d_ws, size_t ws_size,
                              hipStream_t stream) {
    const float* f     = (const float*)d_in[0];
    const float* w1    = (const float*)d_in[1];
    const float* b1    = (const float*)d_in[2];
    const float* gamma = (const float*)d_in[3];
    const float* beta  = (const float*)d_in[4];
    const float* rmean = (const float*)d_in[5];
    const float* rvar  = (const float*)d_in[6];
    const float* w2    = (const float*)d_in[7];
    const float* b2    = (const float*)d_in[8];
    float* out = (float*)d_out;

    unsigned short* fX = (unsigned short*)d_ws;              // 8 MB bf16 frag-order
    unsigned short* gX = fX + (size_t)NB * NM * NC;          // 8 MB bf16 frag-order

    hipLaunchKernelGGL(k_prep_f, dim3(512), dim3(256), 0, stream, f, fX);
    hipLaunchKernelGGL(k_prep_g, dim3(256), dim3(256), 0, stream, fX, w1, gX);
    hipLaunchKernelGGL(k_attn,   dim3(512), dim3(256), 0, stream,
                       fX, gX, w1, b1, gamma, beta, rmean, rvar, w2, b2, out);
}